// Round 18
// baseline (37.225 us; speedup 1.0000x reference)
//
#include <hip/hip_runtime.h>
#include <math.h>

// PersistenceLoss: BCE(y_true, y_pred) + 0.005 * topo
// topo: per 64x64 patch sort both tensors' values, mean squared diff of
// aligned order statistics. B=64, H=W=512 -> 4096 patches of 4096 elems.
//
// COUNTING-SORT + EVENT-HISTOGRAM (no sorts, no dependent walks):
//   Quantize to NB=512 uniform bins (monotone; topo abs err ~3e-6 << 2e-2).
//   Per patch (one 512-thread block; 4 blocks/CU hides barriers):
//     0. issue ALL 8 float4 global loads at kernel entry (MLP; LDS-zero
//        phase + barrier run under the in-flight loads)
//     1. LDS histograms, 2-way privatized; E zeroed in same initial pass
//     2. packed block-scan, 1 bin/thread -> inclusive CDFs in registers
//     3. scatter events E[CA]+=1, E[CB]-=1 (disjoint array: no barrier
//        between scan and scatter)
//     4. block-scan of E (8 ranks/thread) -> D(r); topo = sum D(r)^2
//   Identity: QA(r) = #{a : CA(a) <= r} = prefix_sum(events)(r).
//   BCE fused. Two-kernel finish (R12 lesson: same-address device atomics
//   + fence serialize cross-XCD ~150us; a 2nd launch is cheaper).

#define THREADS 512
#define NB 512
#define PATCH_N 4096
#define NBLOCKS 4096

typedef unsigned int u32;

__global__ __launch_bounds__(THREADS, 8) void patch_hist_kernel(
    const float* __restrict__ y_true,
    const float* __restrict__ y_pred,
    float2* __restrict__ partials)
{
    // SH layout: [HA0(512) | HB0(512) | HA1(512) | HB1(512)] = 2048 ints
    __shared__ int SH[4 * NB];
    __shared__ int E[4100];         // event array over ranks 0..4096
    __shared__ u32 wsum[8];         // packed per-wave totals (A<<16 | B)
    __shared__ int wsumE[8];
    __shared__ float rsum[16];

    const int bp = blockIdx.x;       // patch id 0..4095
    const int bb = bp >> 6;          // batch index
    const int p  = bp & 63;          // patch within image
    const int pr = p >> 3;
    const int pc = p & 7;
    const size_t base = (size_t)bb * (512 * 512)
                      + (size_t)pr * (64 * 512)
                      + (size_t)pc * 64;
    const int t = threadIdx.x;
    const int lane = t & 63;
    const int wid  = t >> 6;         // 0..7

    // ---- 0: issue all global loads FIRST (latency hides under zero+bar) --
    const size_t rowbase = base + (size_t)(t >> 3) * 512 + (size_t)(t & 7) * 8;
    const float4 va0 = *reinterpret_cast<const float4*>(y_true + rowbase);
    const float4 va1 = *reinterpret_cast<const float4*>(y_true + rowbase + 4);
    const float4 vb0 = *reinterpret_cast<const float4*>(y_pred + rowbase);
    const float4 vb1 = *reinterpret_cast<const float4*>(y_pred + rowbase + 4);

    // ---- 1a: zero hist (2048 ints) + event (4096 ints) arrays ----
    {
        int4 z = make_int4(0, 0, 0, 0);
        reinterpret_cast<int4*>(SH)[t] = z;            // 2048 ints
        reinterpret_cast<int4*>(E)[t] = z;             // first 2048 ints
        reinterpret_cast<int4*>(E)[t + 512] = z;       // next 2048 ints
        if (t == 0) E[4096] = 0;
    }
    __syncthreads();

    // ---- 1b: fused BCE + privatized histogram ----
    const int hoff = (t & 256) ? 2 * NB : 0;   // waves 0-3 vs 4-7
    float bce = 0.0f;
    {
        float ya[8] = {va0.x, va0.y, va0.z, va0.w, va1.x, va1.y, va1.z, va1.w};
        float yb[8] = {vb0.x, vb0.y, vb0.z, vb0.w, vb1.x, vb1.y, vb1.z, vb1.w};
        #pragma unroll
        for (int i = 0; i < 8; ++i) {
            float yt = ya[i], yp = yb[i];
            float pcl = fminf(fmaxf(yp, 1e-7f), 1.0f - 1e-7f);
            // log1pf(-p) == logf(1-p): Sterbenz-exact for p>=0.5; __logf =
            // v_log_f32 + mul. BCE abs err ~1e-6 << threshold.
            float L1 = __logf(pcl);
            float L0 = __logf(1.0f - pcl);
            bce -= L0 + yt * (L1 - L0);
            // v_cvt_u32_f32 saturates negatives to 0; values < 1 so *NB < NB
            unsigned ba = min((unsigned)(yt * (float)NB), NB - 1u);
            unsigned bn = min((unsigned)(yp * (float)NB), NB - 1u);
            atomicAdd(&SH[hoff + ba], 1);
            atomicAdd(&SH[hoff + NB + bn], 1);
        }
    }
    __syncthreads();

    // ---- 2: packed CDF scan: thread t owns bin t (copies merged at read) --
    // packed value = (A << 16) | B; partial sums <= 4096 -> no carry.
    const u32 va_ = (u32)(SH[t] + SH[2 * NB + t]);
    const u32 vb_ = (u32)(SH[NB + t] + SH[3 * NB + t]);
    const u32 v = (va_ << 16) | vb_;
    u32 ss = v;
    #pragma unroll
    for (int off = 1; off < 64; off <<= 1) {
        u32 x = __shfl_up(ss, off, 64);
        if (lane >= off) ss += x;
    }
    if (lane == 63) wsum[wid] = ss;
    __syncthreads();
    u32 wb = 0;
    #pragma unroll
    for (int w = 0; w < 7; ++w)
        if (wid > w) wb += wsum[w];
    const u32 cdf = wb + ss;          // inclusive packed CDF at bin t

    // ---- 3: scatter events (E disjoint from SH: no barrier needed) ----
    atomicAdd(&E[cdf >> 16], 1);
    atomicAdd(&E[cdf & 0xFFFFu], -1);
    __syncthreads();

    // ---- 4: inclusive scan of E over r=0..4095; topo += D(r)^2 ----
    // thread t owns r in [t*8, t*8+8)
    int el[8];
    {
        const int4* ep = reinterpret_cast<const int4*>(E + t * 8);
        int4 e0 = ep[0], e1 = ep[1];
        el[0]=e0.x; el[1]=e0.y; el[2]=e0.z; el[3]=e0.w;
        el[4]=e1.x; el[5]=e1.y; el[6]=e1.z; el[7]=e1.w;
    }
    int es = 0;
    #pragma unroll
    for (int k = 0; k < 8; ++k) {
        es += el[k];
        el[k] = es;          // local inclusive
    }
    int ess = es;
    #pragma unroll
    for (int off = 1; off < 64; off <<= 1) {
        int x = __shfl_up(ess, off, 64);
        if (lane >= off) ess += x;
    }
    if (lane == 63) wsumE[wid] = ess;
    __syncthreads();
    int ewb = 0;
    #pragma unroll
    for (int w = 0; w < 7; ++w)
        if (wid > w) ewb += wsumE[w];
    const int ebase = ewb + ess - es;    // exclusive base
    float sq = 0.0f;
    #pragma unroll
    for (int k = 0; k < 8; ++k) {
        float d = (float)(ebase + el[k]);   // D(r) in bin units
        sq = fmaf(d, d, sq);
    }

    // ---- block reduction (no barrier needed before rsum write: rsum
    //      untouched earlier, wsumE reads complete per-thread) ----
    #pragma unroll
    for (int off = 32; off >= 1; off >>= 1) {
        bce += __shfl_down(bce, off, 64);
        sq  += __shfl_down(sq, off, 64);
    }
    if (lane == 0) { rsum[wid] = bce; rsum[8 + wid] = sq; }
    __syncthreads();
    if (t == 0) {
        float bsum = 0.0f, qsum = 0.0f;
        #pragma unroll
        for (int w = 0; w < 8; ++w) { bsum += rsum[w]; qsum += rsum[8 + w]; }
        const float inv_nb2 = 1.0f / ((float)NB * (float)NB);
        partials[bp] = make_float2(bsum, qsum * inv_nb2);
    }
}

__global__ __launch_bounds__(256) void final_reduce_kernel(
    const float2* __restrict__ partials,
    float* __restrict__ out)
{
    __shared__ float rb[256];
    __shared__ float rs[256];
    const int tid = threadIdx.x;
    float bsum = 0.0f, ssum = 0.0f;
    for (int i = tid; i < NBLOCKS; i += 256) {
        float2 v = partials[i];
        bsum += v.x;
        ssum += v.y;
    }
    rb[tid] = bsum;
    rs[tid] = ssum;
    __syncthreads();
    for (int off = 128; off > 0; off >>= 1) {
        if (tid < off) {
            rb[tid] += rb[tid + off];
            rs[tid] += rs[tid + off];
        }
        __syncthreads();
    }
    if (tid == 0) {
        // BCE mean and topo mean share denominator 64*512*512 = 16777216
        out[0] = (rb[0] + 0.005f * rs[0]) * (1.0f / 16777216.0f);
    }
}

extern "C" void kernel_launch(void* const* d_in, const int* in_sizes, int n_in,
                              void* d_out, int out_size, void* d_ws, size_t ws_size,
                              hipStream_t stream) {
    const float* y_true = (const float*)d_in[0];
    const float* y_pred = (const float*)d_in[1];
    float* out = (float*)d_out;
    float2* partials = (float2*)d_ws;   // 4096 * 8 B = 32 KB

    hipLaunchKernelGGL(patch_hist_kernel, dim3(NBLOCKS), dim3(THREADS), 0, stream,
                       y_true, y_pred, partials);
    hipLaunchKernelGGL(final_reduce_kernel, dim3(1), dim3(256), 0, stream,
                       partials, out);
}

// Round 19
// 36.723 us; speedup vs baseline: 1.0137x; 1.0137x over previous
//
#include <hip/hip_runtime.h>
#include <math.h>

// PersistenceLoss: BCE(y_true, y_pred) + 0.005 * topo
// topo: per 64x64 patch sort both tensors' values, mean squared diff of
// aligned order statistics. B=64, H=W=512 -> 4096 patches of 4096 elems.
//
// COUNTING-SORT + EVENT-HISTOGRAM (no sorts, no dependent walks):
//   Quantize to NB=256 uniform bins (monotone; topo abs err ~4e-7 << 2e-2).
//   Per patch, one 256-THREAD block (4 waves) x 16 elems/thread:
//   LDS ~18.8KB -> 8 blocks/CU at the 32-wave cap. Barriers sync only 4
//   waves; 8 independent blocks interleave the serial atomic/scan phases
//   (R15/R18 lesson: overlap granularity, not per-thread chain length,
//   is the binding constraint).
//     1. LDS histograms HA,HB (atomics); E zeroed in same initial pass
//     2. packed block-scan, EXACTLY 1 bin/thread -> inclusive CDFs in regs
//     3. scatter events E[CA]+=1, E[CB]-=1 (disjoint array, no extra bar)
//     4. block-scan of E (16 ranks/thread) -> D(r); topo = sum D(r)^2
//   Identity: QA(r) = #{a : CA(a) <= r} = prefix_sum(events)(r).
//   BCE fused into load. Two-kernel finish (R12 lesson: same-address device
//   atomics + fence serialize cross-XCD ~150us; a 2nd launch is cheaper).

#define THREADS 256
#define NB 256
#define PATCH_N 4096
#define NBLOCKS 4096

typedef unsigned int u32;

__global__ __launch_bounds__(THREADS) void patch_hist_kernel(
    const float* __restrict__ y_true,
    const float* __restrict__ y_pred,
    float2* __restrict__ partials)
{
    __shared__ int SH[2 * NB];      // HA = SH[0..NB), HB = SH[NB..2NB)
    __shared__ int E[4100];         // event array over ranks 0..4096
    __shared__ u32 wsum[4];         // packed per-wave totals (A<<16 | B)
    __shared__ int wsumE[4];
    __shared__ float rsum[8];

    const int bp = blockIdx.x;       // patch id 0..4095
    const int bb = bp >> 6;          // batch index
    const int p  = bp & 63;          // patch within image
    const int pr = p >> 3;
    const int pc = p & 7;
    const size_t base = (size_t)bb * (512 * 512)
                      + (size_t)pr * (64 * 512)
                      + (size_t)pc * 64;
    const int t = threadIdx.x;
    const int lane = t & 63;
    const int wid  = t >> 6;         // 0..3

    // ---- zero hist (512 ints) + event (4096+ ints) arrays ----
    {
        int4 z = make_int4(0, 0, 0, 0);
        if (t < 128) reinterpret_cast<int4*>(SH)[t] = z;   // 512 ints
        reinterpret_cast<int4*>(E)[t] = z;                 // 1024 ints
        reinterpret_cast<int4*>(E)[t + 256] = z;
        reinterpret_cast<int4*>(E)[t + 512] = z;
        reinterpret_cast<int4*>(E)[t + 768] = z;           // 4096 ints
        if (t == 0) E[4096] = 0;
    }
    __syncthreads();

    // ---- load 16 elems/thread: fused BCE + histogram build ----
    // 4 threads per 64-float row: row = t>>2, col = (t&3)*16
    const size_t rowbase = base + (size_t)(t >> 2) * 512 + (size_t)(t & 3) * 16;
    float bce = 0.0f;
    #pragma unroll
    for (int q = 0; q < 4; ++q) {
        float4 va = *reinterpret_cast<const float4*>(y_true + rowbase + q * 4);
        float4 vb = *reinterpret_cast<const float4*>(y_pred + rowbase + q * 4);
        float ya[4] = {va.x, va.y, va.z, va.w};
        float yb[4] = {vb.x, vb.y, vb.z, vb.w};
        #pragma unroll
        for (int i = 0; i < 4; ++i) {
            float yt = ya[i], yp = yb[i];
            float pcl = fminf(fmaxf(yp, 1e-7f), 1.0f - 1e-7f);
            // log1pf(-p) == logf(1-p): Sterbenz-exact for p>=0.5; __logf =
            // v_log_f32 + mul. BCE abs err ~1e-6 << threshold.
            float L1 = __logf(pcl);
            float L0 = __logf(1.0f - pcl);
            bce -= L0 + yt * (L1 - L0);
            // v_cvt_u32_f32 saturates negatives to 0; values < 1 so *NB < NB
            unsigned ba = min((unsigned)(yt * (float)NB), NB - 1u);
            unsigned bn = min((unsigned)(yp * (float)NB), NB - 1u);
            atomicAdd(&SH[ba], 1);
            atomicAdd(&SH[NB + bn], 1);
        }
    }
    __syncthreads();

    // ---- packed CDF scan: thread t owns bin t of both hists ----
    // packed value = (A << 16) | B; partial sums <= 4096 -> no carry.
    const u32 v = ((u32)SH[t] << 16) | (u32)SH[NB + t];
    u32 ss = v;
    #pragma unroll
    for (int off = 1; off < 64; off <<= 1) {
        u32 x = __shfl_up(ss, off, 64);
        if (lane >= off) ss += x;
    }
    if (lane == 63) wsum[wid] = ss;
    __syncthreads();
    u32 wb = 0;
    #pragma unroll
    for (int w = 0; w < 3; ++w)
        if (wid > w) wb += wsum[w];
    const u32 cdf = wb + ss;          // inclusive packed CDF at bin t

    // ---- scatter events (E disjoint from SH: no barrier needed) ----
    atomicAdd(&E[cdf >> 16], 1);
    atomicAdd(&E[cdf & 0xFFFFu], -1);
    __syncthreads();

    // ---- inclusive scan of E over r=0..4095; topo += D(r)^2 ----
    // thread t owns r in [t*16, t*16+16)
    int el[16];
    {
        const int4* ep = reinterpret_cast<const int4*>(E + t * 16);
        int4 e0 = ep[0], e1 = ep[1], e2 = ep[2], e3 = ep[3];
        el[0]=e0.x;  el[1]=e0.y;  el[2]=e0.z;  el[3]=e0.w;
        el[4]=e1.x;  el[5]=e1.y;  el[6]=e1.z;  el[7]=e1.w;
        el[8]=e2.x;  el[9]=e2.y;  el[10]=e2.z; el[11]=e2.w;
        el[12]=e3.x; el[13]=e3.y; el[14]=e3.z; el[15]=e3.w;
    }
    int es = 0;
    #pragma unroll
    for (int k = 0; k < 16; ++k) {
        es += el[k];
        el[k] = es;          // local inclusive
    }
    int ess = es;
    #pragma unroll
    for (int off = 1; off < 64; off <<= 1) {
        int x = __shfl_up(ess, off, 64);
        if (lane >= off) ess += x;
    }
    if (lane == 63) wsumE[wid] = ess;
    __syncthreads();
    int ewb = 0;
    #pragma unroll
    for (int w = 0; w < 3; ++w)
        if (wid > w) ewb += wsumE[w];
    const int ebase = ewb + ess - es;    // exclusive base
    float sq = 0.0f;
    #pragma unroll
    for (int k = 0; k < 16; ++k) {
        float d = (float)(ebase + el[k]);   // D(r) in bin units
        sq = fmaf(d, d, sq);
    }

    // ---- block reduction ----
    #pragma unroll
    for (int off = 32; off >= 1; off >>= 1) {
        bce += __shfl_down(bce, off, 64);
        sq  += __shfl_down(sq, off, 64);
    }
    if (lane == 0) { rsum[wid] = bce; rsum[4 + wid] = sq; }
    __syncthreads();
    if (t == 0) {
        const float inv_nb2 = 1.0f / ((float)NB * (float)NB);
        partials[bp] = make_float2(rsum[0] + rsum[1] + rsum[2] + rsum[3],
                                   (rsum[4] + rsum[5] + rsum[6] + rsum[7]) * inv_nb2);
    }
}

__global__ __launch_bounds__(256) void final_reduce_kernel(
    const float2* __restrict__ partials,
    float* __restrict__ out)
{
    __shared__ float rb[256];
    __shared__ float rs[256];
    const int tid = threadIdx.x;
    float bsum = 0.0f, ssum = 0.0f;
    for (int i = tid; i < NBLOCKS; i += 256) {
        float2 v = partials[i];
        bsum += v.x;
        ssum += v.y;
    }
    rb[tid] = bsum;
    rs[tid] = ssum;
    __syncthreads();
    for (int off = 128; off > 0; off >>= 1) {
        if (tid < off) {
            rb[tid] += rb[tid + off];
            rs[tid] += rs[tid + off];
        }
        __syncthreads();
    }
    if (tid == 0) {
        // BCE mean and topo mean share denominator 64*512*512 = 16777216
        out[0] = (rb[0] + 0.005f * rs[0]) * (1.0f / 16777216.0f);
    }
}

extern "C" void kernel_launch(void* const* d_in, const int* in_sizes, int n_in,
                              void* d_out, int out_size, void* d_ws, size_t ws_size,
                              hipStream_t stream) {
    const float* y_true = (const float*)d_in[0];
    const float* y_pred = (const float*)d_in[1];
    float* out = (float*)d_out;
    float2* partials = (float2*)d_ws;   // 4096 * 8 B = 32 KB

    hipLaunchKernelGGL(patch_hist_kernel, dim3(NBLOCKS), dim3(THREADS), 0, stream,
                       y_true, y_pred, partials);
    hipLaunchKernelGGL(final_reduce_kernel, dim3(1), dim3(256), 0, stream,
                       partials, out);
}